// Round 2
// baseline (214.234 us; speedup 1.0000x reference)
//
#include <hip/hip_runtime.h>

// Problem constants
#define V_SZ 32000
#define E_SZ 128
#define H_SZ 32
#define L_SZ 64
#define B_SZ 32
#define M_TOT 2048   // L*B rows
#define K2 64        // 2H
#define NVT 125      // V / 256
#define NMT 32       // M_TOT / 64

typedef __bf16 bf16x8 __attribute__((ext_vector_type(8)));
typedef float f32x4 __attribute__((ext_vector_type(4)));

__device__ __forceinline__ unsigned short f2bf(float f) {
    unsigned int u = __float_as_uint(f);
    u += 0x7FFFu + ((u >> 16) & 1u);   // round-to-nearest-even
    return (unsigned short)(u >> 16);
}

// ---------------------------------------------------------------------------
// Kernel 1: X[d][t][b][j] = we[inp[t,b]] . W_d[0:128, j] + bias[j]
// grid 128 (d*64+t), block 1024 (b*32+j)
// ---------------------------------------------------------------------------
__global__ __launch_bounds__(1024) void k_emb_gemm(
    const int* __restrict__ inp, const float* __restrict__ we,
    const float* __restrict__ i2h1, const float* __restrict__ i2h2,
    const float* __restrict__ bias, float* __restrict__ X) {
    const int d = blockIdx.x >> 6;
    const int t = blockIdx.x & 63;
    const int tid = threadIdx.x;
    const int b = tid >> 5, j = tid & 31;
    const float* W = d ? i2h2 : i2h1;
    __shared__ float Wl[E_SZ * H_SZ];
    for (int i = tid; i < E_SZ * H_SZ; i += 1024) Wl[i] = W[i];
    __syncthreads();
    const int idx = inp[t * B_SZ + b];
    const float* er = we + (size_t)idx * E_SZ;
    float acc = bias[j];
#pragma unroll
    for (int k0 = 0; k0 < E_SZ; k0 += 4) {
        f32x4 e4 = *(const f32x4*)(er + k0);
        acc += e4.x * Wl[(k0 + 0) * H_SZ + j];
        acc += e4.y * Wl[(k0 + 1) * H_SZ + j];
        acc += e4.z * Wl[(k0 + 2) * H_SZ + j];
        acc += e4.w * Wl[(k0 + 3) * H_SZ + j];
    }
    X[((d * L_SZ + t) * B_SZ + b) * H_SZ + j] = acc;
}

// ---------------------------------------------------------------------------
// Kernel 2: transpose+convert h2o (64 x 32000 f32) -> h2oT (32000 x 64 bf16)
// ---------------------------------------------------------------------------
__global__ __launch_bounds__(256) void k_transpose_h2o(
    const float* __restrict__ h2o, unsigned short* __restrict__ h2oT) {
    const int v = blockIdx.x * 256 + threadIdx.x;
    unsigned int* dst = (unsigned int*)(h2oT + (size_t)v * K2);
#pragma unroll
    for (int k = 0; k < K2; k += 2) {
        float a = h2o[(size_t)k * V_SZ + v];
        float b = h2o[(size_t)(k + 1) * V_SZ + v];
        dst[k >> 1] = (unsigned int)f2bf(a) | ((unsigned int)f2bf(b) << 16);
    }
}

// ---------------------------------------------------------------------------
// Kernel 3: recurrence. 32 independent waves, one per block (CU spread).
// h in registers, cross-lane via shfl; X double-buffered; fast tanh.
// ---------------------------------------------------------------------------
__global__ __launch_bounds__(64) void k_rnn(
    const float* __restrict__ X, const float* __restrict__ i2h1,
    const float* __restrict__ i2h2, const float* __restrict__ hinit,
    unsigned short* __restrict__ hcat) {
    const int w = blockIdx.x;          // 0..31
    const int dir = w >> 4;
    const int lane = threadIdx.x;      // 0..63
    const int b = (w & 15) * 2 + (lane >> 5);
    const int j = lane & 31;
    const int srcbase = lane & 32;
    const float* Wf = dir ? i2h2 : i2h1;
    float wh[H_SZ];
#pragma unroll
    for (int k = 0; k < H_SZ; ++k) wh[k] = Wf[(E_SZ + k) * H_SZ + j];
    float h = hinit[j];
    const float* Xd = X + dir * (L_SZ * B_SZ * H_SZ);
    int tt0 = dir ? (L_SZ - 1) : 0;
    float xcur = Xd[(tt0 * B_SZ + b) * H_SZ + j];
    for (int step = 0; step < L_SZ; ++step) {
        const int tt = dir ? (L_SZ - 1 - step) : step;
        int tn = dir ? (L_SZ - 2 - step) : (step + 1);
        tn = tn < 0 ? 0 : (tn > L_SZ - 1 ? L_SZ - 1 : tn);
        float xnext = Xd[(tn * B_SZ + b) * H_SZ + j];   // prefetch next step
        hcat[(tt * B_SZ + b) * K2 + dir * H_SZ + j] = f2bf(h);
        float a0 = xcur;
        float a1 = 0.f, a2 = 0.f, a3 = 0.f;
#pragma unroll
        for (int k = 0; k < H_SZ; k += 4) {
            a0 += __shfl(h, srcbase | k, 64) * wh[k];
            a1 += __shfl(h, srcbase | (k + 1), 64) * wh[k + 1];
            a2 += __shfl(h, srcbase | (k + 2), 64) * wh[k + 2];
            a3 += __shfl(h, srcbase | (k + 3), 64) * wh[k + 3];
        }
        float x2 = (a0 + a1) + (a2 + a3);
        // tanh(x) = 1 - 2/(e^{2x}+1); overflow-safe (e=inf -> 1, e=0 -> -1)
        float e = __expf(2.f * x2);
        h = 1.f - 2.f * __builtin_amdgcn_rcpf(e + 1.f);
        xcur = xnext;
    }
}

// ---------------------------------------------------------------------------
// Shared GEMM tile: block tile 64 rows x 256 cols, K=64. 4 waves (2m x 2n),
// wave tile 32x128 -> acc[2][8] fragments of 16x16x32 bf16 MFMA.
// A = hcat (M x 64 row-major), B^T = h2oT (V x 64 row-major).
// C layout: row = m*16 + (lane>>4)*4 + reg, col = n*16 + (lane&15).
// ---------------------------------------------------------------------------
__device__ __forceinline__ void gemm_tile(
    const __bf16* __restrict__ hcat, const __bf16* __restrict__ h2oT,
    int rowbase, int colbase, int wm, int wn, int lane, f32x4 acc[2][8]) {
    const int lg = lane >> 4, lr = lane & 15;
    bf16x8 af[2][2];
#pragma unroll
    for (int m = 0; m < 2; ++m) {
        int row = rowbase + wm * 32 + m * 16 + lr;
#pragma unroll
        for (int kh = 0; kh < 2; ++kh)
            af[m][kh] = *(const bf16x8*)(hcat + row * K2 + kh * 32 + lg * 8);
    }
#pragma unroll
    for (int n = 0; n < 8; ++n) {
        int col = colbase + wn * 128 + n * 16 + lr;
        const __bf16* bp = h2oT + (size_t)col * K2 + lg * 8;
        bf16x8 b0 = *(const bf16x8*)(bp);
        bf16x8 b1 = *(const bf16x8*)(bp + 32);
#pragma unroll
        for (int m = 0; m < 2; ++m) {
            acc[m][n] = __builtin_amdgcn_mfma_f32_16x16x32_bf16(af[m][0], b0, acc[m][n], 0, 0, 0);
            acc[m][n] = __builtin_amdgcn_mfma_f32_16x16x32_bf16(af[m][1], b1, acc[m][n], 0, 0, 0);
        }
    }
}

// ---------------------------------------------------------------------------
// Kernel 4 (pass A): per (row, vtile) max and sum-exp partials.
// grid (125, 32), block 256.
// ---------------------------------------------------------------------------
__global__ __launch_bounds__(256) void k_pass_a(
    const __bf16* __restrict__ hcat, const __bf16* __restrict__ h2oT,
    float* __restrict__ Amax, float* __restrict__ Asum) {
    const int tid = threadIdx.x;
    const int wave = tid >> 6, lane = tid & 63;
    const int wm = wave >> 1, wn = wave & 1;
    const int lg = lane >> 4, lr = lane & 15;
    const int rowbase = blockIdx.y * 64, colbase = blockIdx.x * 256;
    f32x4 acc[2][8];
#pragma unroll
    for (int m = 0; m < 2; ++m)
#pragma unroll
        for (int n = 0; n < 8; ++n) acc[m][n] = (f32x4){0.f, 0.f, 0.f, 0.f};
    gemm_tile(hcat, h2oT, rowbase, colbase, wm, wn, lane, acc);

    __shared__ float tmax[2][64];
    __shared__ float tsum[2][64];

    float rmax[2][4];
#pragma unroll
    for (int m = 0; m < 2; ++m)
#pragma unroll
        for (int r = 0; r < 4; ++r) {
            float mv = acc[m][0][r];
#pragma unroll
            for (int n = 1; n < 8; ++n) mv = fmaxf(mv, acc[m][n][r]);
            rmax[m][r] = mv;
        }
#pragma unroll
    for (int mask = 1; mask < 16; mask <<= 1)
#pragma unroll
        for (int m = 0; m < 2; ++m)
#pragma unroll
            for (int r = 0; r < 4; ++r)
                rmax[m][r] = fmaxf(rmax[m][r], __shfl_xor(rmax[m][r], mask, 64));
    if (lr == 0) {
#pragma unroll
        for (int m = 0; m < 2; ++m)
#pragma unroll
            for (int r = 0; r < 4; ++r)
                tmax[wn][wm * 32 + m * 16 + lg * 4 + r] = rmax[m][r];
    }
    __syncthreads();
    float rs[2][4];
#pragma unroll
    for (int m = 0; m < 2; ++m)
#pragma unroll
        for (int r = 0; r < 4; ++r) {
            int row = wm * 32 + m * 16 + lg * 4 + r;
            float cm = fmaxf(tmax[0][row], tmax[1][row]);
            float s = 0.f;
#pragma unroll
            for (int n = 0; n < 8; ++n) s += __expf(acc[m][n][r] - cm);
            rs[m][r] = s;
        }
#pragma unroll
    for (int mask = 1; mask < 16; mask <<= 1)
#pragma unroll
        for (int m = 0; m < 2; ++m)
#pragma unroll
            for (int r = 0; r < 4; ++r)
                rs[m][r] += __shfl_xor(rs[m][r], mask, 64);
    if (lr == 0) {
#pragma unroll
        for (int m = 0; m < 2; ++m)
#pragma unroll
            for (int r = 0; r < 4; ++r)
                tsum[wn][wm * 32 + m * 16 + lg * 4 + r] = rs[m][r];
    }
    __syncthreads();
    if (tid < 64) {
        float gm = fmaxf(tmax[0][tid], tmax[1][tid]);
        float gs = tsum[0][tid] + tsum[1][tid];
        Amax[blockIdx.x * M_TOT + rowbase + tid] = gm;
        Asum[blockIdx.x * M_TOT + rowbase + tid] = gs;
    }
}

// ---------------------------------------------------------------------------
// Kernel 5: reduce partials over 125 v-tiles -> lse[row]
// ---------------------------------------------------------------------------
__global__ __launch_bounds__(256) void k_lse(
    const float* __restrict__ Amax, const float* __restrict__ Asum,
    float* __restrict__ lse) {
    const int row = blockIdx.x * 256 + threadIdx.x;
    float m = -1e30f;
#pragma unroll 5
    for (int i = 0; i < NVT; ++i) m = fmaxf(m, Amax[i * M_TOT + row]);
    float s = 0.f;
#pragma unroll 5
    for (int i = 0; i < NVT; ++i)
        s += Asum[i * M_TOT + row] * __expf(Amax[i * M_TOT + row] - m);
    lse[row] = m + logf(s);
}

// ---------------------------------------------------------------------------
// Kernel 6 (pass B): recompute logits, write log_softmax = logit - lse.
// Two-chunk LDS repack (33 KB -> 4 blocks/CU) + nontemporal coalesced stores.
// ---------------------------------------------------------------------------
__global__ __launch_bounds__(256) void k_pass_b(
    const __bf16* __restrict__ hcat, const __bf16* __restrict__ h2oT,
    const float* __restrict__ lse, float* __restrict__ out) {
    const int tid = threadIdx.x;
    const int wave = tid >> 6, lane = tid & 63;
    const int wm = wave >> 1, wn = wave & 1;
    const int lg = lane >> 4, lr = lane & 15;
    const int rowbase = blockIdx.y * 64, colbase = blockIdx.x * 256;
    f32x4 acc[2][8];
#pragma unroll
    for (int m = 0; m < 2; ++m)
#pragma unroll
        for (int n = 0; n < 8; ++n) acc[m][n] = (f32x4){0.f, 0.f, 0.f, 0.f};
    gemm_tile(hcat, h2oT, rowbase, colbase, wm, wn, lane, acc);

    float lsev[2][4];
#pragma unroll
    for (int m = 0; m < 2; ++m)
#pragma unroll
        for (int r = 0; r < 4; ++r)
            lsev[m][r] = lse[rowbase + wm * 32 + m * 16 + lg * 4 + r];

    __shared__ float cbuf[32 * 260];   // 33.3 KB; pad 260 breaks conflicts
#pragma unroll
    for (int c = 0; c < 2; ++c) {
        if (c) __syncthreads();        // protect cbuf reuse
#pragma unroll
        for (int n = 0; n < 8; ++n)
#pragma unroll
            for (int r = 0; r < 4; ++r)
                cbuf[(wm * 16 + lg * 4 + r) * 260 + wn * 128 + n * 16 + lr] =
                    acc[c][n][r] - lsev[c][r];
        __syncthreads();
#pragma unroll
        for (int it = 0; it < 8; ++it) {
            int idx4 = it * 256 + tid;     // float4 index in 32x256 chunk
            int lrow = idx4 >> 6;          // 64 float4 per row
            int col = (idx4 & 63) << 2;
            int grow = rowbase + (lrow >> 4) * 32 + c * 16 + (lrow & 15);
            f32x4 v = *(const f32x4*)&cbuf[lrow * 260 + col];
            __builtin_nontemporal_store(
                v, (f32x4*)(out + (size_t)grow * V_SZ + colbase + col));
        }
    }
}

// ---------------------------------------------------------------------------
extern "C" void kernel_launch(void* const* d_in, const int* in_sizes, int n_in,
                              void* d_out, int out_size, void* d_ws, size_t ws_size,
                              hipStream_t stream) {
    (void)in_sizes; (void)n_in; (void)out_size; (void)ws_size;
    const int*   inp   = (const int*)d_in[0];
    const float* we    = (const float*)d_in[1];
    const float* i2h1  = (const float*)d_in[2];
    const float* i2h2  = (const float*)d_in[3];
    const float* h2o   = (const float*)d_in[4];
    const float* bias  = (const float*)d_in[5];
    const float* hinit = (const float*)d_in[6];
    float* out = (float*)d_out;
    char* ws = (char*)d_ws;
    // ws layout (total ~6.94 MB)
    float*          X    = (float*)(ws);                      // 524288 B
    unsigned short* hcat = (unsigned short*)(ws + 524288);    // 262144 B
    unsigned short* h2oT = (unsigned short*)(ws + 786432);    // 4096000 B
    float*          Amax = (float*)(ws + 4882432);            // 1024000 B
    float*          Asum = (float*)(ws + 5906432);            // 1024000 B
    float*          lse  = (float*)(ws + 6930432);            // 8192 B

    k_emb_gemm<<<128, 1024, 0, stream>>>(inp, we, i2h1, i2h2, bias, X);
    k_transpose_h2o<<<NVT, 256, 0, stream>>>(h2o, h2oT);
    k_rnn<<<32, 64, 0, stream>>>(X, i2h1, i2h2, hinit, hcat);
    k_pass_a<<<dim3(NVT, NMT), 256, 0, stream>>>(
        (const __bf16*)hcat, (const __bf16*)h2oT, Amax, Asum);
    k_lse<<<8, 256, 0, stream>>>(Amax, Asum, lse);
    k_pass_b<<<dim3(NVT, NMT), 256, 0, stream>>>(
        (const __bf16*)hcat, (const __bf16*)h2oT, lse, out);
}

// Round 3
// 196.826 us; speedup vs baseline: 1.0884x; 1.0884x over previous
//
#include <hip/hip_runtime.h>

// Problem constants
#define V_SZ 32000
#define E_SZ 128
#define H_SZ 32
#define L_SZ 64
#define B_SZ 32
#define M_TOT 2048   // L*B rows
#define K2 64        // 2H
#define NVT 125      // V / 256
#define NMT 32       // M_TOT / 64

typedef __bf16 bf16x8 __attribute__((ext_vector_type(8)));
typedef float f32x4 __attribute__((ext_vector_type(4)));

__device__ __forceinline__ unsigned short f2bf(float f) {
    unsigned int u = __float_as_uint(f);
    u += 0x7FFFu + ((u >> 16) & 1u);   // round-to-nearest-even
    return (unsigned short)(u >> 16);
}

// ---------------------------------------------------------------------------
// Kernel 1 (merged prep):
//  blocks [0,128):  X[d][t][b][j] = we[inp[t,b]] . W_d[0:128, j] + bias[j]
//  blocks [128,160): transpose+convert h2o (64 x 32000 f32) -> h2oT (32000 x 64 bf16)
// ---------------------------------------------------------------------------
__global__ __launch_bounds__(1024) void k_prep(
    const int* __restrict__ inp, const float* __restrict__ we,
    const float* __restrict__ i2h1, const float* __restrict__ i2h2,
    const float* __restrict__ bias, const float* __restrict__ h2o,
    float* __restrict__ X, unsigned short* __restrict__ h2oT) {
    const int tid = threadIdx.x;
    if (blockIdx.x < 128) {
        const int d = blockIdx.x >> 6;
        const int t = blockIdx.x & 63;
        const int b = tid >> 5, j = tid & 31;
        const float* W = d ? i2h2 : i2h1;
        __shared__ float Wl[E_SZ * H_SZ];
        for (int i = tid; i < E_SZ * H_SZ; i += 1024) Wl[i] = W[i];
        __syncthreads();
        const int idx = inp[t * B_SZ + b];
        const float* er = we + (size_t)idx * E_SZ;
        float acc = bias[j];
#pragma unroll
        for (int k0 = 0; k0 < E_SZ; k0 += 4) {
            f32x4 e4 = *(const f32x4*)(er + k0);
            acc += e4.x * Wl[(k0 + 0) * H_SZ + j];
            acc += e4.y * Wl[(k0 + 1) * H_SZ + j];
            acc += e4.z * Wl[(k0 + 2) * H_SZ + j];
            acc += e4.w * Wl[(k0 + 3) * H_SZ + j];
        }
        X[((d * L_SZ + t) * B_SZ + b) * H_SZ + j] = acc;
    } else {
        const int v = (blockIdx.x - 128) * 1024 + tid;
        if (v < V_SZ) {
            unsigned int* dst = (unsigned int*)(h2oT + (size_t)v * K2);
#pragma unroll
            for (int k = 0; k < K2; k += 2) {
                float a = h2o[(size_t)k * V_SZ + v];
                float b = h2o[(size_t)(k + 1) * V_SZ + v];
                dst[k >> 1] = (unsigned int)f2bf(a) | ((unsigned int)f2bf(b) << 16);
            }
        }
    }
}

// ---------------------------------------------------------------------------
// Kernel 2: recurrence. 32 independent waves, one per block (CU spread).
// h in registers, cross-lane via shfl; X double-buffered; fast tanh.
// ---------------------------------------------------------------------------
__global__ __launch_bounds__(64) void k_rnn(
    const float* __restrict__ X, const float* __restrict__ i2h1,
    const float* __restrict__ i2h2, const float* __restrict__ hinit,
    unsigned short* __restrict__ hcat) {
    const int w = blockIdx.x;          // 0..31
    const int dir = w >> 4;
    const int lane = threadIdx.x;      // 0..63
    const int b = (w & 15) * 2 + (lane >> 5);
    const int j = lane & 31;
    const int srcbase = lane & 32;
    const float* Wf = dir ? i2h2 : i2h1;
    float wh[H_SZ];
#pragma unroll
    for (int k = 0; k < H_SZ; ++k) wh[k] = Wf[(E_SZ + k) * H_SZ + j];
    float h = hinit[j];
    const float* Xd = X + dir * (L_SZ * B_SZ * H_SZ);
    int tt0 = dir ? (L_SZ - 1) : 0;
    float xcur = Xd[(tt0 * B_SZ + b) * H_SZ + j];
    for (int step = 0; step < L_SZ; ++step) {
        const int tt = dir ? (L_SZ - 1 - step) : step;
        int tn = dir ? (L_SZ - 2 - step) : (step + 1);
        tn = tn < 0 ? 0 : (tn > L_SZ - 1 ? L_SZ - 1 : tn);
        float xnext = Xd[(tn * B_SZ + b) * H_SZ + j];   // prefetch next step
        hcat[(tt * B_SZ + b) * K2 + dir * H_SZ + j] = f2bf(h);
        float a0 = xcur;
        float a1 = 0.f, a2 = 0.f, a3 = 0.f;
#pragma unroll
        for (int k = 0; k < H_SZ; k += 4) {
            a0 += __shfl(h, srcbase | k, 64) * wh[k];
            a1 += __shfl(h, srcbase | (k + 1), 64) * wh[k + 1];
            a2 += __shfl(h, srcbase | (k + 2), 64) * wh[k + 2];
            a3 += __shfl(h, srcbase | (k + 3), 64) * wh[k + 3];
        }
        float x2 = (a0 + a1) + (a2 + a3);
        // tanh(x) = 1 - 2/(e^{2x}+1); overflow-safe (e=inf -> 1, e=0 -> -1)
        float e = __expf(2.f * x2);
        h = 1.f - 2.f * __builtin_amdgcn_rcpf(e + 1.f);
        xcur = xnext;
    }
}

// ---------------------------------------------------------------------------
// Shared GEMM tile: block tile 64 rows x 256 cols, K=64. 4 waves (2m x 2n),
// wave tile 32x128 -> acc[2][8] fragments of 16x16x32 bf16 MFMA.
// A = hcat (M x 64 row-major), B^T = h2oT (V x 64 row-major).
// C layout: row = m*16 + (lane>>4)*4 + reg, col = n*16 + (lane&15).
// ---------------------------------------------------------------------------
__device__ __forceinline__ void gemm_tile(
    const __bf16* __restrict__ hcat, const __bf16* __restrict__ h2oT,
    int rowbase, int colbase, int wm, int wn, int lane, f32x4 acc[2][8]) {
    const int lg = lane >> 4, lr = lane & 15;
    bf16x8 af[2][2];
#pragma unroll
    for (int m = 0; m < 2; ++m) {
        int row = rowbase + wm * 32 + m * 16 + lr;
#pragma unroll
        for (int kh = 0; kh < 2; ++kh)
            af[m][kh] = *(const bf16x8*)(hcat + row * K2 + kh * 32 + lg * 8);
    }
#pragma unroll
    for (int n = 0; n < 8; ++n) {
        int col = colbase + wn * 128 + n * 16 + lr;
        const __bf16* bp = h2oT + (size_t)col * K2 + lg * 8;
        bf16x8 b0 = *(const bf16x8*)(bp);
        bf16x8 b1 = *(const bf16x8*)(bp + 32);
#pragma unroll
        for (int m = 0; m < 2; ++m) {
            acc[m][n] = __builtin_amdgcn_mfma_f32_16x16x32_bf16(af[m][0], b0, acc[m][n], 0, 0, 0);
            acc[m][n] = __builtin_amdgcn_mfma_f32_16x16x32_bf16(af[m][1], b1, acc[m][n], 0, 0, 0);
        }
    }
}

// ---------------------------------------------------------------------------
// Kernel 3 (pass A, max-free): per (row, vtile) sum-exp partials.
// Logits are bounded (|logit| <~ 51), so f32 sum(exp) cannot overflow.
// grid (125, 32), block 256.
// ---------------------------------------------------------------------------
__global__ __launch_bounds__(256) void k_pass_a(
    const __bf16* __restrict__ hcat, const __bf16* __restrict__ h2oT,
    float* __restrict__ Asum) {
    const int tid = threadIdx.x;
    const int wave = tid >> 6, lane = tid & 63;
    const int wm = wave >> 1, wn = wave & 1;
    const int lg = lane >> 4, lr = lane & 15;
    const int rowbase = blockIdx.y * 64, colbase = blockIdx.x * 256;
    f32x4 acc[2][8];
#pragma unroll
    for (int m = 0; m < 2; ++m)
#pragma unroll
        for (int n = 0; n < 8; ++n) acc[m][n] = (f32x4){0.f, 0.f, 0.f, 0.f};
    gemm_tile(hcat, h2oT, rowbase, colbase, wm, wn, lane, acc);

    float rs[2][4];
#pragma unroll
    for (int m = 0; m < 2; ++m)
#pragma unroll
        for (int r = 0; r < 4; ++r) {
            float s = 0.f;
#pragma unroll
            for (int n = 0; n < 8; ++n) s += __expf(acc[m][n][r]);
            rs[m][r] = s;
        }
    // reduce across the 16 lanes of the lr group (bits 0..3 of lane)
#pragma unroll
    for (int mask = 1; mask < 16; mask <<= 1)
#pragma unroll
        for (int m = 0; m < 2; ++m)
#pragma unroll
            for (int r = 0; r < 4; ++r)
                rs[m][r] += __shfl_xor(rs[m][r], mask, 64);

    __shared__ float tsum[2][64];
    if (lr == 0) {
#pragma unroll
        for (int m = 0; m < 2; ++m)
#pragma unroll
            for (int r = 0; r < 4; ++r)
                tsum[wn][wm * 32 + m * 16 + lg * 4 + r] = rs[m][r];
    }
    __syncthreads();
    if (tid < 64)
        Asum[blockIdx.x * M_TOT + rowbase + tid] = tsum[0][tid] + tsum[1][tid];
}

// ---------------------------------------------------------------------------
// Kernel 4: reduce partials over 125 v-tiles -> lse[row] = log(sum)
// ---------------------------------------------------------------------------
__global__ __launch_bounds__(256) void k_lse(
    const float* __restrict__ Asum, float* __restrict__ lse) {
    const int row = blockIdx.x * 256 + threadIdx.x;
    float s = 0.f;
    for (int i = 0; i < NVT; ++i) s += Asum[i * M_TOT + row];
    lse[row] = logf(s);
}

// ---------------------------------------------------------------------------
// Kernel 5 (pass B): recompute logits, write log_softmax = logit - lse.
// Two-chunk LDS repack (33 KB -> 4 blocks/CU) + plain coalesced f32x4 stores.
// ---------------------------------------------------------------------------
__global__ __launch_bounds__(256) void k_pass_b(
    const __bf16* __restrict__ hcat, const __bf16* __restrict__ h2oT,
    const float* __restrict__ lse, float* __restrict__ out) {
    const int tid = threadIdx.x;
    const int wave = tid >> 6, lane = tid & 63;
    const int wm = wave >> 1, wn = wave & 1;
    const int lg = lane >> 4, lr = lane & 15;
    const int rowbase = blockIdx.y * 64, colbase = blockIdx.x * 256;
    f32x4 acc[2][8];
#pragma unroll
    for (int m = 0; m < 2; ++m)
#pragma unroll
        for (int n = 0; n < 8; ++n) acc[m][n] = (f32x4){0.f, 0.f, 0.f, 0.f};
    gemm_tile(hcat, h2oT, rowbase, colbase, wm, wn, lane, acc);

    float lsev[2][4];
#pragma unroll
    for (int m = 0; m < 2; ++m)
#pragma unroll
        for (int r = 0; r < 4; ++r)
            lsev[m][r] = lse[rowbase + wm * 32 + m * 16 + lg * 4 + r];

    __shared__ float cbuf[32 * 260];   // 33.3 KB; pad 260 breaks conflicts
#pragma unroll
    for (int c = 0; c < 2; ++c) {
        if (c) __syncthreads();        // protect cbuf reuse
#pragma unroll
        for (int n = 0; n < 8; ++n)
#pragma unroll
            for (int r = 0; r < 4; ++r)
                cbuf[(wm * 16 + lg * 4 + r) * 260 + wn * 128 + n * 16 + lr] =
                    acc[c][n][r] - lsev[c][r];
        __syncthreads();
#pragma unroll
        for (int it = 0; it < 8; ++it) {
            int idx4 = it * 256 + tid;     // float4 index in 32x256 chunk
            int lrow = idx4 >> 6;          // 64 float4 per row
            int col = (idx4 & 63) << 2;
            int grow = rowbase + (lrow >> 4) * 32 + c * 16 + (lrow & 15);
            f32x4 v = *(const f32x4*)&cbuf[lrow * 260 + col];
            *(f32x4*)(out + (size_t)grow * V_SZ + colbase + col) = v;
        }
    }
}

// ---------------------------------------------------------------------------
extern "C" void kernel_launch(void* const* d_in, const int* in_sizes, int n_in,
                              void* d_out, int out_size, void* d_ws, size_t ws_size,
                              hipStream_t stream) {
    (void)in_sizes; (void)n_in; (void)out_size; (void)ws_size;
    const int*   inp   = (const int*)d_in[0];
    const float* we    = (const float*)d_in[1];
    const float* i2h1  = (const float*)d_in[2];
    const float* i2h2  = (const float*)d_in[3];
    const float* h2o   = (const float*)d_in[4];
    const float* bias  = (const float*)d_in[5];
    const float* hinit = (const float*)d_in[6];
    float* out = (float*)d_out;
    char* ws = (char*)d_ws;
    // ws layout (~5.9 MB)
    float*          X    = (float*)(ws);                      // 524288 B
    unsigned short* hcat = (unsigned short*)(ws + 524288);    // 262144 B
    unsigned short* h2oT = (unsigned short*)(ws + 786432);    // 4096000 B
    float*          Asum = (float*)(ws + 4882432);            // 1024000 B
    float*          lse  = (float*)(ws + 5906432);            // 8192 B

    k_prep<<<160, 1024, 0, stream>>>(inp, we, i2h1, i2h2, bias, h2o, X, h2oT);
    k_rnn<<<32, 64, 0, stream>>>(X, i2h1, i2h2, hinit, hcat);
    k_pass_a<<<dim3(NVT, NMT), 256, 0, stream>>>(
        (const __bf16*)hcat, (const __bf16*)h2oT, Asum);
    k_lse<<<8, 256, 0, stream>>>(Asum, lse);
    k_pass_b<<<dim3(NVT, NMT), 256, 0, stream>>>(
        (const __bf16*)hcat, (const __bf16*)h2oT, lse, out);
}